// Round 6
// baseline (393.360 us; speedup 1.0000x reference)
//
#include <hip/hip_runtime.h>

#define BB 16
#define HW 4096
#define DIMC 256
#define NHEAD 8
#define CPH 8
#define NQKV 192
#define SCALE 0.17677669529663687f

typedef __attribute__((ext_vector_type(8))) short bf16x8;
typedef __attribute__((ext_vector_type(4))) float f32x4;
typedef __attribute__((ext_vector_type(2))) float f32x2;

__device__ inline unsigned short f2b(float f) {
  union { float f; unsigned int u; } x; x.f = f;
  unsigned int r = x.u + 0x7FFFu + ((x.u >> 16) & 1u);
  return (unsigned short)(r >> 16);
}
__device__ inline float b2f(unsigned short u) {
  union { unsigned int u; float f; } x; x.u = ((unsigned int)u) << 16;
  return x.f;
}
__device__ inline void async_copy16(const void* g, void* l) {
  __builtin_amdgcn_global_load_lds((const __attribute__((address_space(1))) void*)g,
                                   (__attribute__((address_space(3))) void*)l, 16, 0, 0);
}

// ---------------- K0a: x (B,256k,4096s) fp32 -> xT (B,4096s,256k) bf16 ----------------
__global__ __launch_bounds__(256) void cast_xT(const float* __restrict__ x,
                                               unsigned short* __restrict__ xT) {
  __shared__ float Xs[64][69];
  const int b = blockIdx.z;
  const int k0 = blockIdx.y * 64;
  const int s0 = blockIdx.x * 64;
  const int tid = threadIdx.x;
  const float* xb = x + (size_t)b * (DIMC * HW);
#pragma unroll
  for (int i = 0; i < 4; ++i) {
    int idx = tid + i * 256;
    int kr = idx >> 4, f = idx & 15;
    float4 v = *(const float4*)&xb[(size_t)(k0 + kr) * HW + s0 + f * 4];
    Xs[kr][f * 4 + 0] = v.x; Xs[kr][f * 4 + 1] = v.y;
    Xs[kr][f * 4 + 2] = v.z; Xs[kr][f * 4 + 3] = v.w;
  }
  __syncthreads();
  unsigned short* ob = xT + (size_t)b * (HW * DIMC);
#pragma unroll
  for (int i = 0; i < 2; ++i) {
    int slot = tid + i * 256;
    int sr = slot >> 3, g8 = slot & 7;
    unsigned short pk[8];
#pragma unroll
    for (int j = 0; j < 8; ++j) pk[j] = f2b(Xs[g8 * 8 + j][sr]);
    *(uint4*)&ob[(size_t)(s0 + sr) * DIMC + k0 + g8 * 8] = *(uint4*)pk;
  }
}

// ---------------- K0b: qkv_w -> bf16 A-fragment-swizzled ; block 24 builds prep ----------------
// prep layout (floats): [0,864)   Afp[c][p][12] : (I + w1)[c][p][rs], 16B-aligned rows
//                       [864,960) Vb[c][12]     : dcb + dc1b
//                       [960,1056) Rb[n][12]    : rpb
__global__ __launch_bounds__(256) void cast_qw(const float* __restrict__ qw,
                                               unsigned short* __restrict__ qwf,
                                               const float* __restrict__ dcb,
                                               const float* __restrict__ w1,
                                               const float* __restrict__ dc1b,
                                               const float* __restrict__ rpb,
                                               float* __restrict__ prep) {
  if (blockIdx.x == 24) {
    for (int e = threadIdx.x; e < 1056; e += 256) {
      float v = 0.f;
      if (e < 864) {
        int cp = e / 12, rs = e - cp * 12;           // cp = c*9+p
        if (rs < 9) v = w1[cp * 9 + rs] + ((cp % 9) == rs ? 1.f : 0.f);
      } else if (e < 960) {
        int i = e - 864; int c = i / 12, p = i - c * 12;
        if (p < 9) v = dcb[c * 9 + p] + dc1b[c * 9 + p];
      } else {
        int i = e - 960; int n = i / 12, p = i - n * 12;
        if (p < 9) v = rpb[n * 9 + p];
      }
      prep[e] = v;
    }
    return;
  }
  int t = blockIdx.x * 256 + threadIdx.x;  // 6144
  int lane = t & 63;
  int cell = t >> 6;  // band*8 + c32
  int m = lane & 15, g = lane >> 4;
  int band = cell >> 3, c32 = cell & 7;
  int j = band * 16 + m;
  int k = c32 * 32 + g * 8;
  unsigned short pk[8];
#pragma unroll
  for (int i = 0; i < 8; ++i) pk[i] = f2b(qw[j * 256 + k + i]);
  *(uint4*)&qwf[(size_t)t * 8] = *(uint4*)pk;
}

// ---------------- K0c: proj_w (256,64) -> bf16 A-fragment-swizzled ----------------
__global__ __launch_bounds__(256) void cast_pw(const float* __restrict__ pw,
                                               unsigned short* __restrict__ pwf) {
  int t = blockIdx.x * 256 + threadIdx.x;  // 2048
  int lane = t & 63;
  int cell = t >> 6;  // band*2 + c32
  int m = lane & 15, g = lane >> 4;
  int band = cell >> 1, c32 = cell & 1;
  int d = band * 16 + m;
  int j = c32 * 32 + g * 8;
  unsigned short pk[8];
#pragma unroll
  for (int i = 0; i < 8; ++i) pk[i] = f2b(pw[d * 64 + j + i]);
  *(uint4*)&pwf[(size_t)t * 8] = *(uint4*)pk;
}

// ---------------- K1: qkv GEMM via bf16 MFMA ----------------
__global__ __launch_bounds__(256) void qkv_mfma(const unsigned short* __restrict__ xT,
                                                const unsigned short* __restrict__ qwf,
                                                const float* __restrict__ qb,
                                                unsigned short* __restrict__ qkvt) {
  __shared__ unsigned short Bs[128 * 256];
  const int b = blockIdx.y;
  const int s_blk = blockIdx.x * 128;
  const int tid = threadIdx.x;
  const int wave = tid >> 6, lane = tid & 63;

  {
    const int row_in = lane >> 5, cst = lane & 31;
#pragma unroll
    for (int ii = 0; ii < 16; ++ii) {
      int i = wave * 16 + ii;
      int s_row = 2 * i + row_in;
      int mem_chunk = (cst & 24) | ((cst ^ s_row) & 7);
      const unsigned short* src =
          xT + ((size_t)b * HW + s_blk + s_row) * DIMC + mem_chunk * 8;
      async_copy16(src, (char*)Bs + i * 1024);
    }
  }
  __syncthreads();

  f32x4 acc[3][8];
#pragma unroll
  for (int t = 0; t < 3; ++t)
#pragma unroll
    for (int st = 0; st < 8; ++st) acc[t][st] = (f32x4){0.f, 0.f, 0.f, 0.f};

  const int n = lane & 15, g = lane >> 4;
#pragma unroll
  for (int c32 = 0; c32 < 8; ++c32) {
    bf16x8 af[3];
#pragma unroll
    for (int t = 0; t < 3; ++t) {
      int band = wave * 3 + t;
      af[t] = *(const bf16x8*)(qwf + ((size_t)(band * 8 + c32) * 64 + lane) * 8);
    }
#pragma unroll
    for (int st = 0; st < 8; ++st) {
      int s_row = st * 16 + n;
      int mc = c32 * 4 + g;
      int stc = (mc & 24) | ((mc ^ s_row) & 7);
      bf16x8 bf = *(const bf16x8*)&Bs[s_row * 256 + stc * 8];
#pragma unroll
      for (int t = 0; t < 3; ++t)
        acc[t][st] = __builtin_amdgcn_mfma_f32_16x16x32_bf16(af[t], bf, acc[t][st], 0, 0, 0);
    }
  }

  unsigned short* ob = qkvt + (size_t)b * (NQKV * HW);
#pragma unroll
  for (int t = 0; t < 3; ++t) {
    int j0 = (wave * 3 + t) * 16 + g * 4;
#pragma unroll
    for (int st = 0; st < 8; ++st) {
      int s = s_blk + st * 16 + n;
#pragma unroll
      for (int r = 0; r < 4; ++r) {
        float v = acc[t][st][r] + qb[j0 + r];
        ob[(size_t)(j0 + r) * HW + s] = f2b(v);
      }
    }
  }
}

// ---------------- K2 v8: channel-in-wave, packed-f32 math ----------------
// R5 post-mortem: bank conflicts fixed (7.2M->0.9M) but VALU-busy TIME is the
// invariant (~44us across all structures) -> VALU-issue-bound. v8: express the
// K/V conv math and probability accumulate as ext_vector_type(2) float ops so the
// backend emits v_pk_fma_f32/v_pk_mul_f32 (gfx90a+ packed f32): 324 scalar fma
// issues/thread -> 162 packed. A-rows read as explicit float4 (2x ds_read_b128 +
// b32 per 9-float row instead of 9x b32): 81 -> 27 LDS ops per phase.
// Structure (lane=(pix<<3)|c, shuffle butterfly, padded hal2/Qs2) unchanged.
__global__ __launch_bounds__(512, 4) void attn_kernel(const unsigned short* __restrict__ qkvt,
                                                      const float* __restrict__ prep,
                                                      unsigned short* __restrict__ aoT) {
  __shared__ float2 hal2[16][6][21];          // kk(0-7)/vv(8-15); (y, y+4) pairs. 16128 B
  __shared__ __align__(16) float wA[8][108];  // (I+w1), 12-stride rows. 3456 B
  __shared__ float Kbs[8][12], Vbs[8][12];    // per-channel bases. 768 B
  __shared__ float2 Qs2[8][73];               // q*SCALE, (set0,set1) pairs. 4672 B
  __shared__ unsigned short ot[128][8];       // transpose buffer for aoT write. 2048 B

  const int bn = blockIdx.x;   // b*8+n
  const int tile = blockIdx.y; // 0..31 : 8 y-tiles x 4 x-tiles
  const int b = bn >> 3, n = bn & 7;
  const int h0 = (tile >> 2) * 8, w0 = (tile & 3) * 16;
  const int tid = threadIdx.x;
  const int w = tid >> 6, lane = tid & 63;
  const int c = lane & 7;          // channel (within head)
  const int pi = lane >> 3;        // pixel-within-wave 0..7
  const int pidx = w * 8 + pi;     // pixel 0..63 within set
  const int pr = pidx >> 4;        // row 0..3 (set0); set1 = +4
  const int pc = pidx & 15;        // col 0..15
  const unsigned short* fb = qkvt + ((size_t)b * NQKV + n * 24) * HW;

  // stage A (identity pre-baked) : 864 floats
  for (int e = tid; e < 864; e += 512) ((float*)wA)[e] = prep[e];

  // stage K/V bases: Vbs = dcb+dc1b, Kbs = Vbs + rpb[n]
  if (tid < 96) {
    int cc = tid / 12, p = tid - cc * 12;
    float d = prep[864 + tid];
    Vbs[cc][p] = d;
    Kbs[cc][p] = d + prep[960 + n * 12 + p];
  }

  // stage q tile: 8 ch x 64 px x 2 sets, coalesced, pre-scaled
  {
    int cq = tid >> 6, px = tid & 63;
    int sp = (h0 + (px >> 4)) * 64 + w0 + (px & 15);
    float v0 = b2f(fb[(size_t)cq * HW + sp]);
    float v1 = b2f(fb[(size_t)cq * HW + sp + 256]);
    Qs2[cq][px] = make_float2(SCALE * v0, SCALE * v1);
  }

  // stage halos: 16 bufs x 10 rows x 18 cols -> float2 rows (y, y+4)
  for (int e = tid; e < 2880; e += 512) {
    int cb = e / 180;
    int rem = e - cb * 180;
    int y = rem / 18, xx = rem - y * 18;
    int gy = h0 - 1 + y, gx = w0 - 1 + xx;
    float v = 0.f;
    if ((unsigned)gy < 64u && (unsigned)gx < 64u)
      v = b2f(fb[(size_t)(8 + cb) * HW + gy * 64 + gx]);
    if (y < 6) hal2[cb][y][xx].x = v;
    if (y >= 4) hal2[cb][y - 4][xx].y = v;
  }
  __syncthreads();

  const float* wAc = &wA[c][0];
  const f32x2 qc2 = *(const f32x2*)&Qs2[c][pidx];

  f32x2 a2[9];  // logits then probabilities, (set0,set1) packed

  // ---- K phase: packed conv + q*k, butterfly-summed over c (masks 1,2,4) ----
  {
    f32x2 t2[9];
#pragma unroll
    for (int dy = 0; dy < 3; ++dy)
#pragma unroll
      for (int dx = 0; dx < 3; ++dx)
        t2[dy * 3 + dx] = *(const f32x2*)&hal2[c][pr + dy][pc + dx];
#pragma unroll
    for (int p = 0; p < 9; ++p) {
      const float4 a0 = *(const float4*)&wAc[p * 12];
      const float4 a1 = *(const float4*)&wAc[p * 12 + 4];
      const float a8 = wAc[p * 12 + 8];
      float base = Kbs[c][p];
      f32x2 k2 = {base, base};
      k2 += a0.x * t2[0]; k2 += a0.y * t2[1]; k2 += a0.z * t2[2];
      k2 += a0.w * t2[3]; k2 += a1.x * t2[4]; k2 += a1.y * t2[5];
      k2 += a1.z * t2[6]; k2 += a1.w * t2[7]; k2 += a8  * t2[8];
      f32x2 l2 = qc2 * k2;
      float lx = l2.x, ly = l2.y;
      lx += __shfl_xor(lx, 1);  ly += __shfl_xor(ly, 1);
      lx += __shfl_xor(lx, 2);  ly += __shfl_xor(ly, 2);
      lx += __shfl_xor(lx, 4);  ly += __shfl_xor(ly, 4);
      a2[p] = (f32x2){lx, ly};
    }
  }

  // ---- softmax: per-lane over p (redundant across the 8 channel-lanes, no sync) ----
  {
    float mx = -1e30f, my = -1e30f;
#pragma unroll
    for (int p = 0; p < 9; ++p) { mx = fmaxf(mx, a2[p].x); my = fmaxf(my, a2[p].y); }
    float dx = 0.f, dy = 0.f;
#pragma unroll
    for (int p = 0; p < 9; ++p) {
      float ex = __expf(a2[p].x - mx); dx += ex;
      float ey = __expf(a2[p].y - my); dy += ey;
      a2[p] = (f32x2){ex, ey};
    }
    f32x2 i2 = {1.f / dx, 1.f / dy};
#pragma unroll
    for (int p = 0; p < 9; ++p) a2[p] *= i2;
  }

  // ---- V phase: packed conv, per-channel output, no reduce needed ----
  {
    f32x2 t2[9];
#pragma unroll
    for (int dy = 0; dy < 3; ++dy)
#pragma unroll
      for (int dx = 0; dx < 3; ++dx)
        t2[dy * 3 + dx] = *(const f32x2*)&hal2[8 + c][pr + dy][pc + dx];
    f32x2 o2 = {0.f, 0.f};
#pragma unroll
    for (int p = 0; p < 9; ++p) {
      const float4 a0 = *(const float4*)&wAc[p * 12];
      const float4 a1 = *(const float4*)&wAc[p * 12 + 4];
      const float a8 = wAc[p * 12 + 8];
      float base = Vbs[c][p];
      f32x2 v2 = {base, base};
      v2 += a0.x * t2[0]; v2 += a0.y * t2[1]; v2 += a0.z * t2[2];
      v2 += a0.w * t2[3]; v2 += a1.x * t2[4]; v2 += a1.y * t2[5];
      v2 += a1.z * t2[6]; v2 += a1.w * t2[7]; v2 += a8  * t2[8];
      o2 += a2[p] * v2;
    }
    ot[pidx][c] = f2b(o2.x);
    ot[pidx + 64][c] = f2b(o2.y);
  }
  __syncthreads();

  // ---- write aoT[b][s][j=n*8..n*8+7] (16B per pixel) ----
  if (w < 2) {
    int p = w * 64 + lane;
    uint4 val = *(const uint4*)&ot[p][0];
    int sp = (h0 + (p >> 4)) * 64 + w0 + (p & 15);
    *(uint4*)&aoT[((size_t)b * HW + sp) * 64 + n * 8] = val;
  }
}

// ---------------- K3: proj GEMM via bf16 MFMA ----------------
// out(256d x 128s per block) = pw(256x64) * aoT^T; K=64. 4 waves x 4 d-bands x 8 s-tiles.
__global__ __launch_bounds__(256) void proj_mfma(const unsigned short* __restrict__ aoT,
                                                 const unsigned short* __restrict__ pwf,
                                                 const float* __restrict__ pb,
                                                 float* __restrict__ out) {
  __shared__ unsigned short Bs[128 * 64];  // rows 128B, 8 chunks XOR-swizzled
  const int b = blockIdx.y;
  const int s_blk = blockIdx.x * 128;
  const int tid = threadIdx.x;
  const int wave = tid >> 6, lane = tid & 63;

  {
    const int slot = lane & 7, rsub = lane >> 3;
#pragma unroll
    for (int ii = 0; ii < 4; ++ii) {
      int i = wave * 4 + ii;
      int row = 8 * i + rsub;
      int mem_chunk = slot ^ rsub;
      const unsigned short* src =
          aoT + ((size_t)b * HW + s_blk + row) * 64 + mem_chunk * 8;
      async_copy16(src, (char*)Bs + i * 1024);
    }
  }
  __syncthreads();

  f32x4 acc[4][8];
#pragma unroll
  for (int t = 0; t < 4; ++t)
#pragma unroll
    for (int st = 0; st < 8; ++st) acc[t][st] = (f32x4){0.f, 0.f, 0.f, 0.f};

  const int n = lane & 15, g = lane >> 4;
#pragma unroll
  for (int c32 = 0; c32 < 2; ++c32) {
    bf16x8 af[4];
#pragma unroll
    for (int t = 0; t < 4; ++t) {
      int band = wave * 4 + t;
      af[t] = *(const bf16x8*)(pwf + ((size_t)(band * 2 + c32) * 64 + lane) * 8);
    }
#pragma unroll
    for (int st = 0; st < 8; ++st) {
      int s_row = st * 16 + n;
      int mc = c32 * 4 + g;
      int stc = mc ^ (s_row & 7);
      bf16x8 bf = *(const bf16x8*)&Bs[s_row * 64 + stc * 8];
#pragma unroll
      for (int t = 0; t < 4; ++t)
        acc[t][st] = __builtin_amdgcn_mfma_f32_16x16x32_bf16(af[t], bf, acc[t][st], 0, 0, 0);
    }
  }

  float bias[4][4];
#pragma unroll
  for (int t = 0; t < 4; ++t)
#pragma unroll
    for (int r = 0; r < 4; ++r) bias[t][r] = pb[(wave * 4 + t) * 16 + g * 4 + r];

  float* ob = out + ((size_t)b << 20);
#pragma unroll
  for (int t = 0; t < 4; ++t) {
    int d0 = (wave * 4 + t) * 16 + g * 4;
#pragma unroll
    for (int st = 0; st < 8; ++st) {
      int s = s_blk + st * 16 + n;
#pragma unroll
      for (int r = 0; r < 4; ++r)
        ob[(size_t)(d0 + r) * HW + s] = acc[t][st][r] + bias[t][r];
    }
  }
}

extern "C" void kernel_launch(void* const* d_in, const int* in_sizes, int n_in,
                              void* d_out, int out_size, void* d_ws, size_t ws_size,
                              hipStream_t stream) {
  (void)in_sizes; (void)n_in; (void)out_size; (void)ws_size;
  const float* x    = (const float*)d_in[0];
  const float* qw   = (const float*)d_in[5];
  const float* qb   = (const float*)d_in[6];
  const float* dcb  = (const float*)d_in[7];
  const float* w1   = (const float*)d_in[8];
  const float* dc1b = (const float*)d_in[9];
  const float* rpb  = (const float*)d_in[10];
  const float* pw   = (const float*)d_in[11];
  const float* pb   = (const float*)d_in[12];

  // Workspace (time-multiplexed, 64 MiB total = proven-safe R0 size):
  // [0, 25165824)            qkvt bf16 (B,192,4096)          qkv -> attn
  // [25165824, 33554432)     qwf (cast_qw -> qkv, dead after) THEN aoT bf16 (attn -> proj)
  // [33554432, 67108864)     xT bf16 (cast_xT -> qkv, dead)   THEN pwf (cast_pw -> proj)
  // prep (4224 B) lives at the head of d_out: written by cast_qw, read by attn,
  // dead before proj_mfma overwrites the full output buffer.
  unsigned short* qkvt = (unsigned short*)d_ws;
  unsigned short* qwf  = (unsigned short*)((char*)d_ws + 25165824);
  unsigned short* aoT  = (unsigned short*)((char*)d_ws + 25165824);
  unsigned short* xT   = (unsigned short*)((char*)d_ws + 33554432);
  unsigned short* pwf  = (unsigned short*)((char*)d_ws + 33554432);
  float* prep          = (float*)d_out;

  cast_qw<<<25, 256, 0, stream>>>(qw, qwf, dcb, w1, dc1b, rpb, prep);
  cast_xT<<<dim3(64, 4, BB), 256, 0, stream>>>(x, xT);
  qkv_mfma<<<dim3(32, BB), 256, 0, stream>>>(xT, qwf, qb, qkvt);
  cast_pw<<<8, 256, 0, stream>>>(pw, pwf);
  attn_kernel<<<dim3(BB * NHEAD, 32), 512, 0, stream>>>(qkvt, prep, aoT);
  proj_mfma<<<dim3(32, BB), 256, 0, stream>>>(aoT, pwf, pb, (float*)d_out);
}

// Round 7
// 225.722 us; speedup vs baseline: 1.7427x; 1.7427x over previous
//
#include <hip/hip_runtime.h>

#define BB 16
#define HW 4096
#define DIMC 256
#define NHEAD 8
#define CPH 8
#define NQKV 192
#define SCALE 0.17677669529663687f

typedef __attribute__((ext_vector_type(8))) short bf16x8;
typedef __attribute__((ext_vector_type(4))) float f32x4;

__device__ inline unsigned short f2b(float f) {
  union { float f; unsigned int u; } x; x.f = f;
  unsigned int r = x.u + 0x7FFFu + ((x.u >> 16) & 1u);
  return (unsigned short)(r >> 16);
}
__device__ inline float b2f(unsigned short u) {
  union { unsigned int u; float f; } x; x.u = ((unsigned int)u) << 16;
  return x.f;
}
__device__ inline void async_copy16(const void* g, void* l) {
  __builtin_amdgcn_global_load_lds((const __attribute__((address_space(1))) void*)g,
                                   (__attribute__((address_space(3))) void*)l, 16, 0, 0);
}

// ---------------- K0a: x (B,256k,4096s) fp32 -> xT (B,4096s,256k) bf16 ----------------
__global__ __launch_bounds__(256) void cast_xT(const float* __restrict__ x,
                                               unsigned short* __restrict__ xT) {
  __shared__ float Xs[64][69];
  const int b = blockIdx.z;
  const int k0 = blockIdx.y * 64;
  const int s0 = blockIdx.x * 64;
  const int tid = threadIdx.x;
  const float* xb = x + (size_t)b * (DIMC * HW);
#pragma unroll
  for (int i = 0; i < 4; ++i) {
    int idx = tid + i * 256;
    int kr = idx >> 4, f = idx & 15;
    float4 v = *(const float4*)&xb[(size_t)(k0 + kr) * HW + s0 + f * 4];
    Xs[kr][f * 4 + 0] = v.x; Xs[kr][f * 4 + 1] = v.y;
    Xs[kr][f * 4 + 2] = v.z; Xs[kr][f * 4 + 3] = v.w;
  }
  __syncthreads();
  unsigned short* ob = xT + (size_t)b * (HW * DIMC);
#pragma unroll
  for (int i = 0; i < 2; ++i) {
    int slot = tid + i * 256;
    int sr = slot >> 3, g8 = slot & 7;
    unsigned short pk[8];
#pragma unroll
    for (int j = 0; j < 8; ++j) pk[j] = f2b(Xs[g8 * 8 + j][sr]);
    *(uint4*)&ob[(size_t)(s0 + sr) * DIMC + k0 + g8 * 8] = *(uint4*)pk;
  }
}

// ---------------- K0b: combined weight prep ----------------
// blocks 0..23: qkv_w -> qwf (bf16 A-fragment-swizzled)
// block 24:     prep table (A=I+w1 @12-stride, Vb=dcb+dc1b, Rb=rpb)
// blocks 25..32: proj_w -> pwf
__global__ __launch_bounds__(256) void cast_all(const float* __restrict__ qw,
                                                unsigned short* __restrict__ qwf,
                                                const float* __restrict__ dcb,
                                                const float* __restrict__ w1,
                                                const float* __restrict__ dc1b,
                                                const float* __restrict__ rpb,
                                                float* __restrict__ prep,
                                                const float* __restrict__ pw,
                                                unsigned short* __restrict__ pwf) {
  if (blockIdx.x == 24) {
    for (int e = threadIdx.x; e < 1056; e += 256) {
      float v = 0.f;
      if (e < 864) {
        int cp = e / 12, rs = e - cp * 12;           // cp = c*9+p
        if (rs < 9) v = w1[cp * 9 + rs] + ((cp % 9) == rs ? 1.f : 0.f);
      } else if (e < 960) {
        int i = e - 864; int c = i / 12, p = i - c * 12;
        if (p < 9) v = dcb[c * 9 + p] + dc1b[c * 9 + p];
      } else {
        int i = e - 960; int n = i / 12, p = i - n * 12;
        if (p < 9) v = rpb[n * 9 + p];
      }
      prep[e] = v;
    }
    return;
  }
  if (blockIdx.x >= 25) {
    int t = (blockIdx.x - 25) * 256 + threadIdx.x;  // 2048
    int lane = t & 63;
    int cell = t >> 6;  // band*2 + c32
    int m = lane & 15, g = lane >> 4;
    int band = cell >> 1, c32 = cell & 1;
    int d = band * 16 + m;
    int j = c32 * 32 + g * 8;
    unsigned short pk[8];
#pragma unroll
    for (int i = 0; i < 8; ++i) pk[i] = f2b(pw[d * 64 + j + i]);
    *(uint4*)&pwf[(size_t)t * 8] = *(uint4*)pk;
    return;
  }
  int t = blockIdx.x * 256 + threadIdx.x;  // 6144
  int lane = t & 63;
  int cell = t >> 6;  // band*8 + c32
  int m = lane & 15, g = lane >> 4;
  int band = cell >> 3, c32 = cell & 7;
  int j = band * 16 + m;
  int k = c32 * 32 + g * 8;
  unsigned short pk[8];
#pragma unroll
  for (int i = 0; i < 8; ++i) pk[i] = f2b(qw[j * 256 + k + i]);
  *(uint4*)&qwf[(size_t)t * 8] = *(uint4*)pk;
}

// ---------------- K1: qkv GEMM via bf16 MFMA ----------------
__global__ __launch_bounds__(256) void qkv_mfma(const unsigned short* __restrict__ xT,
                                                const unsigned short* __restrict__ qwf,
                                                const float* __restrict__ qb,
                                                unsigned short* __restrict__ qkvt) {
  __shared__ unsigned short Bs[128 * 256];
  const int b = blockIdx.y;
  const int s_blk = blockIdx.x * 128;
  const int tid = threadIdx.x;
  const int wave = tid >> 6, lane = tid & 63;

  {
    const int row_in = lane >> 5, cst = lane & 31;
#pragma unroll
    for (int ii = 0; ii < 16; ++ii) {
      int i = wave * 16 + ii;
      int s_row = 2 * i + row_in;
      int mem_chunk = (cst & 24) | ((cst ^ s_row) & 7);
      const unsigned short* src =
          xT + ((size_t)b * HW + s_blk + s_row) * DIMC + mem_chunk * 8;
      async_copy16(src, (char*)Bs + i * 1024);
    }
  }
  __syncthreads();

  f32x4 acc[3][8];
#pragma unroll
  for (int t = 0; t < 3; ++t)
#pragma unroll
    for (int st = 0; st < 8; ++st) acc[t][st] = (f32x4){0.f, 0.f, 0.f, 0.f};

  const int n = lane & 15, g = lane >> 4;
#pragma unroll
  for (int c32 = 0; c32 < 8; ++c32) {
    bf16x8 af[3];
#pragma unroll
    for (int t = 0; t < 3; ++t) {
      int band = wave * 3 + t;
      af[t] = *(const bf16x8*)(qwf + ((size_t)(band * 8 + c32) * 64 + lane) * 8);
    }
#pragma unroll
    for (int st = 0; st < 8; ++st) {
      int s_row = st * 16 + n;
      int mc = c32 * 4 + g;
      int stc = (mc & 24) | ((mc ^ s_row) & 7);
      bf16x8 bf = *(const bf16x8*)&Bs[s_row * 256 + stc * 8];
#pragma unroll
      for (int t = 0; t < 3; ++t)
        acc[t][st] = __builtin_amdgcn_mfma_f32_16x16x32_bf16(af[t], bf, acc[t][st], 0, 0, 0);
    }
  }

  unsigned short* ob = qkvt + (size_t)b * (NQKV * HW);
#pragma unroll
  for (int t = 0; t < 3; ++t) {
    int j0 = (wave * 3 + t) * 16 + g * 4;
#pragma unroll
    for (int st = 0; st < 8; ++st) {
      int s = s_blk + st * 16 + n;
#pragma unroll
      for (int r = 0; r < 4; ++r) {
        float v = acc[t][st][r] + qb[j0 + r];
        ob[(size_t)(j0 + r) * HW + s] = f2b(v);
      }
    }
  }
}

// ---------------- K2 v9: fused attn(8 heads) + proj ----------------
// R6 post-mortem: packed-f32 spilled (VGPR pinned 64, hbm_bytes 30x) -> math reverted
// to R5's proven scalar form (69.8us). This round targets the OTHER 157us: one block
// handles a 128-px tile for ALL 8 heads (grid 4096->512), accumulating the 128x64
// aoT tile in LDS (XOR-swizzled chunks, = proj_mfma's Bs layout), then runs proj's
// K=64 MFMA + fp32 store as an epilogue. Deletes proj_mfma kernel, the 64MB aoT HBM
// round-trip, and the ot-transpose.
__global__ __launch_bounds__(512, 4) void attn_proj(const unsigned short* __restrict__ qkvt,
                                                    const float* __restrict__ prep,
                                                    const unsigned short* __restrict__ pwf,
                                                    const float* __restrict__ pb,
                                                    float* __restrict__ out) {
  __shared__ float2 hal2[16][6][21];          // kk/vv halos, (y,y+4) pairs. 16128 B
  __shared__ __align__(16) float wA[8][108];  // (I+w1), 12-stride rows. 3456 B
  __shared__ float Kbs[8][8][12];             // [n][c][p] K bases. 3072 B
  __shared__ float Vbs[8][12];                // V bases. 384 B
  __shared__ float2 Qs2[8][73];               // q*SCALE pairs. 4672 B
  __shared__ unsigned short Ao[128][64];      // attn-out tile, chunk^=(row&7). 16384 B

  const int b = blockIdx.x;    // batch
  const int tile = blockIdx.y; // 0..31
  const int h0 = (tile >> 2) * 8, w0 = (tile & 3) * 16;
  const int tid = threadIdx.x;
  const int w = tid >> 6, lane = tid & 63;
  const int c = lane & 7;          // channel within head
  const int pi = lane >> 3;        // pixel-within-wave
  const int pidx = w * 8 + pi;     // pixel 0..63 within set
  const int pr = pidx >> 4, pc = pidx & 15;
  const unsigned short* fbase = qkvt + (size_t)b * (NQKV * HW);

  // one-time stages
  for (int e = tid; e < 864; e += 512) ((float*)wA)[e] = prep[e];
  if (tid < 96) {
    int cc = tid / 12, p = tid - cc * 12;
    Vbs[cc][p] = prep[864 + tid];
  }
  for (int e = tid; e < 768; e += 512) {
    int nn = e / 96, r = e - nn * 96;
    int p = r % 12;
    Kbs[nn][r / 12][p] = prep[864 + r] + prep[960 + nn * 12 + p];
  }

  for (int n = 0; n < 8; ++n) {
    const unsigned short* fb = fbase + (size_t)n * 24 * HW;
    __syncthreads();  // prev head's hal2/Qs2 readers done before restage

    // stage q tile: 8 ch x 64 px x 2 sets, coalesced, pre-scaled
    {
      int cq = tid >> 6, px = tid & 63;
      int sp = (h0 + (px >> 4)) * 64 + w0 + (px & 15);
      float v0 = b2f(fb[(size_t)cq * HW + sp]);
      float v1 = b2f(fb[(size_t)cq * HW + sp + 256]);
      Qs2[cq][px] = make_float2(SCALE * v0, SCALE * v1);
    }
    // stage halos
    for (int e = tid; e < 2880; e += 512) {
      int cb = e / 180;
      int rem = e - cb * 180;
      int y = rem / 18, xx = rem - y * 18;
      int gy = h0 - 1 + y, gx = w0 - 1 + xx;
      float v = 0.f;
      if ((unsigned)gy < 64u && (unsigned)gx < 64u)
        v = b2f(fb[(size_t)(8 + cb) * HW + gy * 64 + gx]);
      if (y < 6) hal2[cb][y][xx].x = v;
      if (y >= 4) hal2[cb][y - 4][xx].y = v;
    }
    __syncthreads();

    const float* wAc = &wA[c][0];
    const float2 qc = Qs2[c][pidx];
    const float* Kbn = &Kbs[n][c][0];

    // ---- K phase: per-lane channel partials, butterfly-summed over c ----
    float ax[9], ay[9];
    {
      float2 t[9];
#pragma unroll
      for (int dy = 0; dy < 3; ++dy)
#pragma unroll
        for (int dx = 0; dx < 3; ++dx)
          t[dy * 3 + dx] = hal2[c][pr + dy][pc + dx];
#pragma unroll
      for (int p = 0; p < 9; ++p) {
        float base = Kbn[p];
        float kx = base, ky = base;
#pragma unroll
        for (int rs = 0; rs < 9; ++rs) {
          float a = wAc[p * 12 + rs];
          kx = fmaf(a, t[rs].x, kx);
          ky = fmaf(a, t[rs].y, ky);
        }
        float lx = qc.x * kx;
        float lyv = qc.y * ky;
        lx += __shfl_xor(lx, 1);  lyv += __shfl_xor(lyv, 1);
        lx += __shfl_xor(lx, 2);  lyv += __shfl_xor(lyv, 2);
        lx += __shfl_xor(lx, 4);  lyv += __shfl_xor(lyv, 4);
        ax[p] = lx; ay[p] = lyv;
      }
    }

    // ---- softmax ----
    {
      float mx = -1e30f, my = -1e30f;
#pragma unroll
      for (int p = 0; p < 9; ++p) { mx = fmaxf(mx, ax[p]); my = fmaxf(my, ay[p]); }
      float dx = 0.f, dy = 0.f;
#pragma unroll
      for (int p = 0; p < 9; ++p) {
        ax[p] = __expf(ax[p] - mx); dx += ax[p];
        ay[p] = __expf(ay[p] - my); dy += ay[p];
      }
      float ix = 1.f / dx, iy = 1.f / dy;
#pragma unroll
      for (int p = 0; p < 9; ++p) { ax[p] *= ix; ay[p] *= iy; }
    }

    // ---- V phase -> Ao (XOR-swizzled chunk = head^(row&7)) ----
    {
      float2 t[9];
#pragma unroll
      for (int dy = 0; dy < 3; ++dy)
#pragma unroll
        for (int dx = 0; dx < 3; ++dx)
          t[dy * 3 + dx] = hal2[8 + c][pr + dy][pc + dx];
      float ocx = 0.f, ocy = 0.f;
#pragma unroll
      for (int p = 0; p < 9; ++p) {
        float base = Vbs[c][p];
        float vx = base, vy = base;
#pragma unroll
        for (int rs = 0; rs < 9; ++rs) {
          float a = wAc[p * 12 + rs];
          vx = fmaf(a, t[rs].x, vx);
          vy = fmaf(a, t[rs].y, vy);
        }
        ocx = fmaf(ax[p], vx, ocx);
        ocy = fmaf(ay[p], vy, ocy);
      }
      int col = ((n ^ (pidx & 7)) << 3) + c;   // (pidx+64)&7 == pidx&7
      Ao[pidx][col] = f2b(ocx);
      Ao[pidx + 64][col] = f2b(ocy);
    }
  }
  __syncthreads();

  // ---- proj epilogue: out(256d x 128px) = pw(256x64) @ Ao^T, K=64 ----
  f32x4 acc[2][8];
#pragma unroll
  for (int t = 0; t < 2; ++t)
#pragma unroll
    for (int st = 0; st < 8; ++st) acc[t][st] = (f32x4){0.f, 0.f, 0.f, 0.f};

  const int nn = lane & 15, g = lane >> 4;
#pragma unroll
  for (int c32 = 0; c32 < 2; ++c32) {
    bf16x8 af[2];
#pragma unroll
    for (int t = 0; t < 2; ++t) {
      int band = w * 2 + t;
      af[t] = *(const bf16x8*)(pwf + ((size_t)(band * 2 + c32) * 64 + lane) * 8);
    }
#pragma unroll
    for (int st = 0; st < 8; ++st) {
      int s_row = st * 16 + nn;
      int stc = (c32 * 4 + g) ^ (s_row & 7);
      bf16x8 bf = *(const bf16x8*)&Ao[s_row][stc * 8];
#pragma unroll
      for (int t = 0; t < 2; ++t)
        acc[t][st] = __builtin_amdgcn_mfma_f32_16x16x32_bf16(af[t], bf, acc[t][st], 0, 0, 0);
    }
  }

  float bias[2][4];
#pragma unroll
  for (int t = 0; t < 2; ++t)
#pragma unroll
    for (int r = 0; r < 4; ++r) bias[t][r] = pb[(w * 2 + t) * 16 + g * 4 + r];

  float* ob = out + ((size_t)b << 20);
#pragma unroll
  for (int t = 0; t < 2; ++t) {
    int d0 = (w * 2 + t) * 16 + g * 4;
#pragma unroll
    for (int st = 0; st < 8; ++st) {
      int sp = (h0 + (st >> 2) * 4 + (st & 3)) * 64 + w0 + nn;
#pragma unroll
      for (int r = 0; r < 4; ++r)
        ob[(size_t)(d0 + r) * HW + sp] = acc[t][st][r] + bias[t][r];
    }
  }
}

extern "C" void kernel_launch(void* const* d_in, const int* in_sizes, int n_in,
                              void* d_out, int out_size, void* d_ws, size_t ws_size,
                              hipStream_t stream) {
  (void)in_sizes; (void)n_in; (void)out_size; (void)ws_size;
  const float* x    = (const float*)d_in[0];
  const float* qw   = (const float*)d_in[5];
  const float* qb   = (const float*)d_in[6];
  const float* dcb  = (const float*)d_in[7];
  const float* w1   = (const float*)d_in[8];
  const float* dc1b = (const float*)d_in[9];
  const float* rpb  = (const float*)d_in[10];
  const float* pw   = (const float*)d_in[11];
  const float* pb   = (const float*)d_in[12];

  // Workspace (64 MiB, proven-safe):
  // [0, 25165824)            qkvt bf16 (B,192,4096)
  // [25165824, 25264128)     qwf  (6144*16 B)
  // [29360128, 29364352)     prep (1056 floats) -- moved OFF d_out (fused kernel
  //                          writes out while other blocks still read prep)
  // [30408704, 30441472)     pwf  (2048*16 B)
  // [33554432, 67108864)     xT bf16 (dead after qkv_mfma)
  unsigned short* qkvt = (unsigned short*)d_ws;
  unsigned short* qwf  = (unsigned short*)((char*)d_ws + 25165824);
  float* prep          = (float*)((char*)d_ws + 29360128);
  unsigned short* pwf  = (unsigned short*)((char*)d_ws + 30408704);
  unsigned short* xT   = (unsigned short*)((char*)d_ws + 33554432);

  cast_all<<<33, 256, 0, stream>>>(qw, qwf, dcb, w1, dc1b, rpb, prep, pw, pwf);
  cast_xT<<<dim3(64, 4, BB), 256, 0, stream>>>(x, xT);
  qkv_mfma<<<dim3(32, BB), 256, 0, stream>>>(xT, qwf, qb, qkvt);
  attn_proj<<<dim3(BB, 32), 512, 0, stream>>>(qkvt, prep, pwf, pb, (float*)d_out);
}

// Round 8
// 207.025 us; speedup vs baseline: 1.9001x; 1.0903x over previous
//
#include <hip/hip_runtime.h>

#define BB 16
#define HW 4096
#define DIMC 256
#define NHEAD 8
#define CPH 8
#define NQKV 192
#define SCALE 0.17677669529663687f

typedef __attribute__((ext_vector_type(8))) short bf16x8;
typedef __attribute__((ext_vector_type(4))) float f32x4;

__device__ inline unsigned short f2b(float f) {
  union { float f; unsigned int u; } x; x.f = f;
  unsigned int r = x.u + 0x7FFFu + ((x.u >> 16) & 1u);
  return (unsigned short)(r >> 16);
}
__device__ inline float b2f(unsigned short u) {
  union { unsigned int u; float f; } x; x.u = ((unsigned int)u) << 16;
  return x.f;
}

// ---------------- K0: combined weight prep ----------------
// blocks 0..23: qkv_w -> qwf (bf16 A-fragment-swizzled)
// block 24:     prep table (A=I+w1 @12-stride, Vb=dcb+dc1b, Rb=rpb)
// blocks 25..32: proj_w -> pwf
__global__ __launch_bounds__(256) void cast_all(const float* __restrict__ qw,
                                                unsigned short* __restrict__ qwf,
                                                const float* __restrict__ dcb,
                                                const float* __restrict__ w1,
                                                const float* __restrict__ dc1b,
                                                const float* __restrict__ rpb,
                                                float* __restrict__ prep,
                                                const float* __restrict__ pw,
                                                unsigned short* __restrict__ pwf) {
  if (blockIdx.x == 24) {
    for (int e = threadIdx.x; e < 1056; e += 256) {
      float v = 0.f;
      if (e < 864) {
        int cp = e / 12, rs = e - cp * 12;           // cp = c*9+p
        if (rs < 9) v = w1[cp * 9 + rs] + ((cp % 9) == rs ? 1.f : 0.f);
      } else if (e < 960) {
        int i = e - 864; int c = i / 12, p = i - c * 12;
        if (p < 9) v = dcb[c * 9 + p] + dc1b[c * 9 + p];
      } else {
        int i = e - 960; int n = i / 12, p = i - n * 12;
        if (p < 9) v = rpb[n * 9 + p];
      }
      prep[e] = v;
    }
    return;
  }
  if (blockIdx.x >= 25) {
    int t = (blockIdx.x - 25) * 256 + threadIdx.x;  // 2048
    int lane = t & 63;
    int cell = t >> 6;  // band*2 + c32
    int m = lane & 15, g = lane >> 4;
    int band = cell >> 1, c32 = cell & 1;
    int d = band * 16 + m;
    int j = c32 * 32 + g * 8;
    unsigned short pk[8];
#pragma unroll
    for (int i = 0; i < 8; ++i) pk[i] = f2b(pw[d * 64 + j + i]);
    *(uint4*)&pwf[(size_t)t * 8] = *(uint4*)pk;
    return;
  }
  int t = blockIdx.x * 256 + threadIdx.x;  // 6144
  int lane = t & 63;
  int cell = t >> 6;  // band*8 + c32
  int m = lane & 15, g = lane >> 4;
  int band = cell >> 3, c32 = cell & 7;
  int j = band * 16 + m;
  int k = c32 * 32 + g * 8;
  unsigned short pk[8];
#pragma unroll
  for (int i = 0; i < 8; ++i) pk[i] = f2b(qw[j * 256 + k + i]);
  *(uint4*)&qwf[(size_t)t * 8] = *(uint4*)pk;
}

// ---------------- K1 v2: qkv GEMM with fused x fp32->bf16 transpose staging ----------
// R7 analysis: cast_xT's 64MB round-trip + a whole launch were pure overhead. Here
// each lane owns one s-column of the 128x256 tile: 128 coalesced dword reads down k
// (wave = 64 consecutive s per instruction), f2b convert (bit-identical to cast_xT),
// pack ushort8, write to the SAME XOR-swizzled Bs slot ((mc&24)|((mc^s_row)&7)) the
// old global_load_lds path produced. MFMA loop unchanged.
__global__ __launch_bounds__(256) void qkv_mfma(const float* __restrict__ x,
                                                const unsigned short* __restrict__ qwf,
                                                const float* __restrict__ qb,
                                                unsigned short* __restrict__ qkvt) {
  __shared__ unsigned short Bs[128 * 256];
  const int b = blockIdx.y;
  const int s_blk = blockIdx.x * 128;
  const int tid = threadIdx.x;
  const int wave = tid >> 6, lane = tid & 63;
  const float* xb = x + (size_t)b * (DIMC * HW);

  {
    const int s_row = (wave & 1) * 64 + lane;   // row within Bs (0..127)
    const int k_base = (wave >> 1) * 128;       // waves 0,1 -> k 0..127; 2,3 -> 128..255
    const float* p = xb + (size_t)k_base * HW + s_blk + s_row;
#pragma unroll
    for (int kc = 0; kc < 16; ++kc) {
      unsigned short pk[8];
#pragma unroll
      for (int j = 0; j < 8; ++j) {
        pk[j] = f2b(*p);
        p += HW;
      }
      int mc = (k_base >> 3) + kc;              // memory chunk 0..31
      int stc = (mc & 24) | ((mc ^ s_row) & 7);
      *(uint4*)&Bs[s_row * 256 + stc * 8] = *(uint4*)pk;
    }
  }
  __syncthreads();

  f32x4 acc[3][8];
#pragma unroll
  for (int t = 0; t < 3; ++t)
#pragma unroll
    for (int st = 0; st < 8; ++st) acc[t][st] = (f32x4){0.f, 0.f, 0.f, 0.f};

  const int n = lane & 15, g = lane >> 4;
#pragma unroll
  for (int c32 = 0; c32 < 8; ++c32) {
    bf16x8 af[3];
#pragma unroll
    for (int t = 0; t < 3; ++t) {
      int band = wave * 3 + t;
      af[t] = *(const bf16x8*)(qwf + ((size_t)(band * 8 + c32) * 64 + lane) * 8);
    }
#pragma unroll
    for (int st = 0; st < 8; ++st) {
      int s_row = st * 16 + n;
      int mc = c32 * 4 + g;
      int stc = (mc & 24) | ((mc ^ s_row) & 7);
      bf16x8 bf = *(const bf16x8*)&Bs[s_row * 256 + stc * 8];
#pragma unroll
      for (int t = 0; t < 3; ++t)
        acc[t][st] = __builtin_amdgcn_mfma_f32_16x16x32_bf16(af[t], bf, acc[t][st], 0, 0, 0);
    }
  }

  unsigned short* ob = qkvt + (size_t)b * (NQKV * HW);
#pragma unroll
  for (int t = 0; t < 3; ++t) {
    int j0 = (wave * 3 + t) * 16 + g * 4;
#pragma unroll
    for (int st = 0; st < 8; ++st) {
      int s = s_blk + st * 16 + n;
#pragma unroll
      for (int r = 0; r < 4; ++r) {
        float v = acc[t][st][r] + qb[j0 + r];
        ob[(size_t)(j0 + r) * HW + s] = f2b(v);
      }
    }
  }
}

// ---------------- K2 v10: fused attn(8 heads)+proj, 64-px tiles ----------------
// R7 post-mortem: grid 512 = 2 blocks/CU = 50% occupancy hard cap (measured 37%).
// v10: 4x16-px tiles -> grid 1024 = 4 blocks/CU; LDS ~25KB (6 blocks would fit);
// 2048 thr/CU = 100% cap. 1 pixel/thread (scalar math, R5-proven form). Ao/proj
// swizzle identical to R7's verified epilogue, now 64 rows (st 0..3).
__global__ __launch_bounds__(512, 4) void attn_proj(const unsigned short* __restrict__ qkvt,
                                                    const float* __restrict__ prep,
                                                    const unsigned short* __restrict__ pwf,
                                                    const float* __restrict__ pb,
                                                    float* __restrict__ out) {
  __shared__ float hal[16][6][20];            // kk/vv halos: 6 rows x 18 cols (pad 20). 7680 B
  __shared__ __align__(16) float wA[8][108];  // (I+w1), 12-stride rows. 3456 B
  __shared__ float Kbs[8][8][12];             // [n][c][p] K bases. 3072 B
  __shared__ float Vbs[8][12];                // V bases. 384 B
  __shared__ float Qs[8][68];                 // q*SCALE. 2176 B
  __shared__ unsigned short Ao[64][64];       // attn-out tile, chunk^=(row&7). 8192 B

  const int b = blockIdx.x;    // batch
  const int ty = blockIdx.y;   // 0..63 : 16 y-tiles x 4 x-tiles
  const int h0 = (ty >> 2) * 4, w0 = (ty & 3) * 16;
  const int tid = threadIdx.x;
  const int w = tid >> 6, lane = tid & 63;
  const int c = lane & 7;          // channel within head
  const int pi = lane >> 3;        // pixel-within-wave
  const int pidx = w * 8 + pi;     // pixel 0..63
  const int pr = pidx >> 4, pc = pidx & 15;
  const unsigned short* fbase = qkvt + (size_t)b * (NQKV * HW);

  // one-time stages
  for (int e = tid; e < 864; e += 512) ((float*)wA)[e] = prep[e];
  if (tid < 96) {
    int cc = tid / 12, p = tid - cc * 12;
    Vbs[cc][p] = prep[864 + tid];
  }
  for (int e = tid; e < 768; e += 512) {
    int nn = e / 96, r = e - nn * 96;
    int p = r % 12;
    Kbs[nn][r / 12][p] = prep[864 + r] + prep[960 + nn * 12 + p];
  }

  for (int n = 0; n < 8; ++n) {
    const unsigned short* fb = fbase + (size_t)n * 24 * HW;
    __syncthreads();  // prev head's hal/Qs readers done before restage

    // stage q tile: 8 ch x 64 px, pre-scaled (wave w stages channel w)
    {
      int cq = tid >> 6, px = tid & 63;
      int sp = (h0 + (px >> 4)) * 64 + w0 + (px & 15);
      Qs[cq][px] = SCALE * b2f(fb[(size_t)cq * HW + sp]);
    }
    // stage halos: 16 bufs x 6 rows x 18 cols
    for (int e = tid; e < 1728; e += 512) {
      int cb = e / 108;
      int rem = e - cb * 108;
      int y = rem / 18, xx = rem - y * 18;
      int gy = h0 - 1 + y, gx = w0 - 1 + xx;
      float v = 0.f;
      if ((unsigned)gy < 64u && (unsigned)gx < 64u)
        v = b2f(fb[(size_t)(8 + cb) * HW + gy * 64 + gx]);
      hal[cb][y][xx] = v;
    }
    __syncthreads();

    const float* wAc = &wA[c][0];
    const float qc = Qs[c][pidx];
    const float* Kbn = &Kbs[n][c][0];

    // ---- K phase: per-lane channel partials, butterfly-summed over c ----
    float ax[9];
    {
      float t[9];
#pragma unroll
      for (int dy = 0; dy < 3; ++dy)
#pragma unroll
        for (int dx = 0; dx < 3; ++dx)
          t[dy * 3 + dx] = hal[c][pr + dy][pc + dx];
#pragma unroll
      for (int p = 0; p < 9; ++p) {
        float kx = Kbn[p];
#pragma unroll
        for (int rs = 0; rs < 9; ++rs)
          kx = fmaf(wAc[p * 12 + rs], t[rs], kx);
        float lx = qc * kx;
        lx += __shfl_xor(lx, 1);
        lx += __shfl_xor(lx, 2);
        lx += __shfl_xor(lx, 4);
        ax[p] = lx;
      }
    }

    // ---- softmax (redundant across the 8 channel-lanes, no sync) ----
    {
      float mx = -1e30f;
#pragma unroll
      for (int p = 0; p < 9; ++p) mx = fmaxf(mx, ax[p]);
      float dx = 0.f;
#pragma unroll
      for (int p = 0; p < 9; ++p) { ax[p] = __expf(ax[p] - mx); dx += ax[p]; }
      float ix = 1.f / dx;
#pragma unroll
      for (int p = 0; p < 9; ++p) ax[p] *= ix;
    }

    // ---- V phase -> Ao (XOR-swizzled chunk = head^(row&7)) ----
    {
      float t[9];
#pragma unroll
      for (int dy = 0; dy < 3; ++dy)
#pragma unroll
        for (int dx = 0; dx < 3; ++dx)
          t[dy * 3 + dx] = hal[8 + c][pr + dy][pc + dx];
      float oc = 0.f;
#pragma unroll
      for (int p = 0; p < 9; ++p) {
        float vx = Vbs[c][p];
#pragma unroll
        for (int rs = 0; rs < 9; ++rs)
          vx = fmaf(wAc[p * 12 + rs], t[rs], vx);
        oc = fmaf(ax[p], vx, oc);
      }
      Ao[pidx][((n ^ (pidx & 7)) << 3) + c] = f2b(oc);
    }
  }
  __syncthreads();

  // ---- proj epilogue: out(256d x 64px) = pw(256x64) @ Ao^T, K=64 ----
  f32x4 acc[2][4];
#pragma unroll
  for (int t = 0; t < 2; ++t)
#pragma unroll
    for (int st = 0; st < 4; ++st) acc[t][st] = (f32x4){0.f, 0.f, 0.f, 0.f};

  const int nn = lane & 15, g = lane >> 4;
#pragma unroll
  for (int c32 = 0; c32 < 2; ++c32) {
    bf16x8 af[2];
#pragma unroll
    for (int t = 0; t < 2; ++t) {
      int band = w * 2 + t;
      af[t] = *(const bf16x8*)(pwf + ((size_t)(band * 2 + c32) * 64 + lane) * 8);
    }
#pragma unroll
    for (int st = 0; st < 4; ++st) {
      int s_row = st * 16 + nn;
      int stc = (c32 * 4 + g) ^ (s_row & 7);
      bf16x8 bf = *(const bf16x8*)&Ao[s_row][stc * 8];
#pragma unroll
      for (int t = 0; t < 2; ++t)
        acc[t][st] = __builtin_amdgcn_mfma_f32_16x16x32_bf16(af[t], bf, acc[t][st], 0, 0, 0);
    }
  }

  float bias[2][4];
#pragma unroll
  for (int t = 0; t < 2; ++t)
#pragma unroll
    for (int r = 0; r < 4; ++r) bias[t][r] = pb[(w * 2 + t) * 16 + g * 4 + r];

  float* ob = out + ((size_t)b << 20);
#pragma unroll
  for (int t = 0; t < 2; ++t) {
    int d0 = (w * 2 + t) * 16 + g * 4;
#pragma unroll
    for (int st = 0; st < 4; ++st) {
      int sp = (h0 + st) * 64 + w0 + nn;
#pragma unroll
      for (int r = 0; r < 4; ++r)
        ob[(size_t)(d0 + r) * HW + sp] = acc[t][st][r] + bias[t][r];
    }
  }
}

extern "C" void kernel_launch(void* const* d_in, const int* in_sizes, int n_in,
                              void* d_out, int out_size, void* d_ws, size_t ws_size,
                              hipStream_t stream) {
  (void)in_sizes; (void)n_in; (void)out_size; (void)ws_size;
  const float* x    = (const float*)d_in[0];
  const float* qw   = (const float*)d_in[5];
  const float* qb   = (const float*)d_in[6];
  const float* dcb  = (const float*)d_in[7];
  const float* w1   = (const float*)d_in[8];
  const float* dc1b = (const float*)d_in[9];
  const float* rpb  = (const float*)d_in[10];
  const float* pw   = (const float*)d_in[11];
  const float* pb   = (const float*)d_in[12];

  // Workspace (64 MiB, proven-safe):
  // [0, 25165824)            qkvt bf16 (B,192,4096)
  // [25165824, 25264128)     qwf  (6144*16 B)
  // [29360128, 29364352)     prep (1056 floats)
  // [30408704, 30441472)     pwf  (2048*16 B)
  // xT eliminated (cast_xT fused into qkv_mfma).
  unsigned short* qkvt = (unsigned short*)d_ws;
  unsigned short* qwf  = (unsigned short*)((char*)d_ws + 25165824);
  float* prep          = (float*)((char*)d_ws + 29360128);
  unsigned short* pwf  = (unsigned short*)((char*)d_ws + 30408704);

  cast_all<<<33, 256, 0, stream>>>(qw, qwf, dcb, w1, dc1b, rpb, prep, pw, pwf);
  qkv_mfma<<<dim3(32, BB), 256, 0, stream>>>(x, qwf, qb, qkvt);
  attn_proj<<<dim3(BB, 64), 512, 0, stream>>>(qkvt, prep, pwf, pb, (float*)d_out);
}

// Round 9
// 182.052 us; speedup vs baseline: 2.1607x; 1.1372x over previous
//
#include <hip/hip_runtime.h>

#define BB 16
#define HW 4096
#define DIMC 256
#define NHEAD 8
#define CPH 8
#define NQKV 192
#define SCALE 0.17677669529663687f

typedef __attribute__((ext_vector_type(8))) short bf16x8;
typedef __attribute__((ext_vector_type(4))) float f32x4;

__device__ inline unsigned short f2b(float f) {
  union { float f; unsigned int u; } x; x.f = f;
  unsigned int r = x.u + 0x7FFFu + ((x.u >> 16) & 1u);
  return (unsigned short)(r >> 16);
}
__device__ inline float b2f(unsigned short u) {
  union { unsigned int u; float f; } x; x.u = ((unsigned int)u) << 16;
  return x.f;
}

// ---------------- K0: combined weight prep ----------------
// blocks 0..23: qkv_w -> qwf (bf16 A-fragment-swizzled)
// block 24:     prep table (A=I+w1 @12-stride, Vb=dcb+dc1b, Rb=rpb)
// blocks 25..32: proj_w -> pwf
__global__ __launch_bounds__(256) void cast_all(const float* __restrict__ qw,
                                                unsigned short* __restrict__ qwf,
                                                const float* __restrict__ dcb,
                                                const float* __restrict__ w1,
                                                const float* __restrict__ dc1b,
                                                const float* __restrict__ rpb,
                                                float* __restrict__ prep,
                                                const float* __restrict__ pw,
                                                unsigned short* __restrict__ pwf) {
  if (blockIdx.x == 24) {
    for (int e = threadIdx.x; e < 1056; e += 256) {
      float v = 0.f;
      if (e < 864) {
        int cp = e / 12, rs = e - cp * 12;           // cp = c*9+p
        if (rs < 9) v = w1[cp * 9 + rs] + ((cp % 9) == rs ? 1.f : 0.f);
      } else if (e < 960) {
        int i = e - 864; int c = i / 12, p = i - c * 12;
        if (p < 9) v = dcb[c * 9 + p] + dc1b[c * 9 + p];
      } else {
        int i = e - 960; int n = i / 12, p = i - n * 12;
        if (p < 9) v = rpb[n * 9 + p];
      }
      prep[e] = v;
    }
    return;
  }
  if (blockIdx.x >= 25) {
    int t = (blockIdx.x - 25) * 256 + threadIdx.x;  // 2048
    int lane = t & 63;
    int cell = t >> 6;  // band*2 + c32
    int m = lane & 15, g = lane >> 4;
    int band = cell >> 1, c32 = cell & 1;
    int d = band * 16 + m;
    int j = c32 * 32 + g * 8;
    unsigned short pk[8];
#pragma unroll
    for (int i = 0; i < 8; ++i) pk[i] = f2b(pw[d * 64 + j + i]);
    *(uint4*)&pwf[(size_t)t * 8] = *(uint4*)pk;
    return;
  }
  int t = blockIdx.x * 256 + threadIdx.x;  // 6144
  int lane = t & 63;
  int cell = t >> 6;  // band*8 + c32
  int m = lane & 15, g = lane >> 4;
  int band = cell >> 3, c32 = cell & 7;
  int j = band * 16 + m;
  int k = c32 * 32 + g * 8;
  unsigned short pk[8];
#pragma unroll
  for (int i = 0; i < 8; ++i) pk[i] = f2b(qw[j * 256 + k + i]);
  *(uint4*)&qwf[(size_t)t * 8] = *(uint4*)pk;
}

// ---------------- K1: qkv GEMM with fused x fp32->bf16 transpose staging (R8-proven) --
__global__ __launch_bounds__(256) void qkv_mfma(const float* __restrict__ x,
                                                const unsigned short* __restrict__ qwf,
                                                const float* __restrict__ qb,
                                                unsigned short* __restrict__ qkvt) {
  __shared__ unsigned short Bs[128 * 256];
  const int b = blockIdx.y;
  const int s_blk = blockIdx.x * 128;
  const int tid = threadIdx.x;
  const int wave = tid >> 6, lane = tid & 63;
  const float* xb = x + (size_t)b * (DIMC * HW);

  {
    const int s_row = (wave & 1) * 64 + lane;   // row within Bs (0..127)
    const int k_base = (wave >> 1) * 128;       // waves 0,1 -> k 0..127; 2,3 -> 128..255
    const float* p = xb + (size_t)k_base * HW + s_blk + s_row;
#pragma unroll
    for (int kc = 0; kc < 16; ++kc) {
      unsigned short pk[8];
#pragma unroll
      for (int j = 0; j < 8; ++j) {
        pk[j] = f2b(*p);
        p += HW;
      }
      int mc = (k_base >> 3) + kc;              // memory chunk 0..31
      int stc = (mc & 24) | ((mc ^ s_row) & 7);
      *(uint4*)&Bs[s_row * 256 + stc * 8] = *(uint4*)pk;
    }
  }
  __syncthreads();

  f32x4 acc[3][8];
#pragma unroll
  for (int t = 0; t < 3; ++t)
#pragma unroll
    for (int st = 0; st < 8; ++st) acc[t][st] = (f32x4){0.f, 0.f, 0.f, 0.f};

  const int n = lane & 15, g = lane >> 4;
#pragma unroll
  for (int c32 = 0; c32 < 8; ++c32) {
    bf16x8 af[3];
#pragma unroll
    for (int t = 0; t < 3; ++t) {
      int band = wave * 3 + t;
      af[t] = *(const bf16x8*)(qwf + ((size_t)(band * 8 + c32) * 64 + lane) * 8);
    }
#pragma unroll
    for (int st = 0; st < 8; ++st) {
      int s_row = st * 16 + n;
      int mc = c32 * 4 + g;
      int stc = (mc & 24) | ((mc ^ s_row) & 7);
      bf16x8 bf = *(const bf16x8*)&Bs[s_row * 256 + stc * 8];
#pragma unroll
      for (int t = 0; t < 3; ++t)
        acc[t][st] = __builtin_amdgcn_mfma_f32_16x16x32_bf16(af[t], bf, acc[t][st], 0, 0, 0);
    }
  }

  unsigned short* ob = qkvt + (size_t)b * (NQKV * HW);
#pragma unroll
  for (int t = 0; t < 3; ++t) {
    int j0 = (wave * 3 + t) * 16 + g * 4;
#pragma unroll
    for (int st = 0; st < 8; ++st) {
      int s = s_blk + st * 16 + n;
#pragma unroll
      for (int r = 0; r < 4; ++r) {
        float v = acc[t][st][r] + qb[j0 + r];
        ob[(size_t)(j0 + r) * HW + s] = f2b(v);
      }
    }
  }
}

// ---------------- K2 v11: quad-pixel attn+proj, A register-resident ----------------
// R8 post-mortem: R7(2px) == R8(1px) == ~84us because both are LDS-issue-bound on the
// per-FMA A broadcast reads (~162 ds_read/thread/head); LDS pipe is per-CU so occupancy
// can't help. v11: A is head-INVARIANT and 81 floats/channel -> keep it in VGPRs for
// the whole kernel at 2 waves/SIMD (launch_bounds(256,2) -> 256-VGPR budget).
// Thread owns a 2x2 pixel quad (4x4 halo window = 16 ds_read w/ immediate offsets).
// LDS/thread/head drops ~200 -> ~45. hal is flat affine-indexed (stride 180 = 20 mod 32,
// max 2-way = free). Staging uses precomputed offsets + async split (issue next head's
// 16 global loads before compute, commit after barrier). Epilogue = R7's verified MFMA
// re-banded for 4 waves. 256 thr, 128-px tile, grid (16,32) = 2 blocks/CU.
__global__ __launch_bounds__(256, 2) void attn_proj(const unsigned short* __restrict__ qkvt,
                                                    const float* __restrict__ prep,
                                                    const unsigned short* __restrict__ pwf,
                                                    const float* __restrict__ pb,
                                                    float* __restrict__ out) {
  __shared__ float hal[2880];              // [cb 16][y 10][x 18] flat, affine slot index. 11520 B
  __shared__ float Rbs[96];                // rpb [n][12]. 384 B
  __shared__ unsigned short Ao[128][64];   // attn-out tile, chunk ^= (row&7). 16384 B

  const int b = blockIdx.x;
  const int ty = blockIdx.y;               // 0..31 : 4 y-tiles x 4 x-tiles... (8 rows x 16 cols)
  const int h0 = (ty >> 2) * 8, w0 = (ty & 3) * 16;
  const int tid = threadIdx.x;
  const int w = tid >> 6;                  // wave id == quad-row (rows 2w, 2w+1)
  const int c = tid & 7;                   // channel
  const int qk = (tid >> 3) & 7;           // quad col (cols 2qk, 2qk+1)
  const unsigned short* fbase = qkvt + (size_t)b * (NQKV * HW);

  if (tid < 96) Rbs[tid] = prep[960 + tid];

  // A = I + w1 for this channel: register-resident for the whole kernel
  float A[81];
  {
    const float* ap = prep + c * 108;
#pragma unroll
    for (int p = 0; p < 9; ++p) {
      float4 a0 = *(const float4*)(ap + p * 12);
      float4 a1 = *(const float4*)(ap + p * 12 + 4);
      A[p*9+0]=a0.x; A[p*9+1]=a0.y; A[p*9+2]=a0.z; A[p*9+3]=a0.w;
      A[p*9+4]=a1.x; A[p*9+5]=a1.y; A[p*9+6]=a1.z; A[p*9+7]=a1.w;
      A[p*9+8]=ap[p*12+8];
    }
  }
  float Vb[9];
#pragma unroll
  for (int p = 0; p < 9; ++p) Vb[p] = prep[864 + c * 12 + p];

  // precomputed staging offsets (head-invariant)
  int hofs[12];
#pragma unroll
  for (int i = 0; i < 12; ++i) {
    int e = tid + i * 256;
    int cb = e / 180;
    int rem = e - cb * 180;
    int y = rem / 18, xx = rem - y * 18;
    int gy = h0 - 1 + y, gx = w0 - 1 + xx;
    bool ok = (e < 2880) && ((unsigned)gy < 64u) && ((unsigned)gx < 64u);
    hofs[i] = ok ? ((8 + cb) * HW + gy * 64 + gx) : -1;
  }
  int gq[4];
#pragma unroll
  for (int dy = 0; dy < 2; ++dy)
#pragma unroll
    for (int dx = 0; dx < 2; ++dx)
      gq[dy * 2 + dx] = c * HW + (h0 + 2 * w + dy) * 64 + w0 + 2 * qk + dx;

  // prefetch head 0
  unsigned short hreg[12], qreg[4];
  {
    const unsigned short* fb = fbase;
#pragma unroll
    for (int i = 0; i < 12; ++i) hreg[i] = fb[hofs[i] < 0 ? 0 : hofs[i]];
#pragma unroll
    for (int i = 0; i < 4; ++i) qreg[i] = fb[gq[i]];
  }

  const int tbase = c * 180 + w * 36 + qk * 2;   // hal window base (rows 2w..2w+3, cols 2qk..2qk+3)

  for (int n = 0; n < 8; ++n) {
    __syncthreads();                       // head n-1 readers done; hal free
    // commit staged halo + q
#pragma unroll
    for (int i = 0; i < 11; ++i)
      hal[tid + i * 256] = (hofs[i] >= 0) ? b2f(hreg[i]) : 0.f;
    if (tid < 64) hal[tid + 11 * 256] = (hofs[11] >= 0) ? b2f(hreg[11]) : 0.f;
    float qc[4];
#pragma unroll
    for (int i = 0; i < 4; ++i) qc[i] = SCALE * b2f(qreg[i]);
    // async prefetch of head n+1 (latency hides under this head's compute)
    if (n < 7) {
      const unsigned short* f2 = fbase + (size_t)(n + 1) * 24 * HW;
#pragma unroll
      for (int i = 0; i < 12; ++i) hreg[i] = f2[hofs[i] < 0 ? 0 : hofs[i]];
#pragma unroll
      for (int i = 0; i < 4; ++i) qreg[i] = f2[gq[i]];
    }
    __syncthreads();

    float Kb[9];
#pragma unroll
    for (int p = 0; p < 9; ++p) Kb[p] = Vb[p] + Rbs[n * 12 + p];

    // ---- K phase: quad conv, butterfly-sum over c (masks 1,2,4) ----
    float ax[4][9];
    {
      float t[16];
#pragma unroll
      for (int i = 0; i < 4; ++i)
#pragma unroll
        for (int j = 0; j < 4; ++j)
          t[i * 4 + j] = hal[tbase + i * 18 + j];
#pragma unroll
      for (int p = 0; p < 9; ++p) {
        float k0 = Kb[p], k1 = Kb[p], k2 = Kb[p], k3 = Kb[p];
#pragma unroll
        for (int ry = 0; ry < 3; ++ry)
#pragma unroll
          for (int rx = 0; rx < 3; ++rx) {
            float a = A[p * 9 + ry * 3 + rx];
            k0 = fmaf(a, t[ry * 4 + rx],           k0);
            k1 = fmaf(a, t[ry * 4 + rx + 1],       k1);
            k2 = fmaf(a, t[(ry + 1) * 4 + rx],     k2);
            k3 = fmaf(a, t[(ry + 1) * 4 + rx + 1], k3);
          }
        float l0 = qc[0] * k0, l1 = qc[1] * k1, l2 = qc[2] * k2, l3 = qc[3] * k3;
        l0 += __shfl_xor(l0, 1); l1 += __shfl_xor(l1, 1); l2 += __shfl_xor(l2, 1); l3 += __shfl_xor(l3, 1);
        l0 += __shfl_xor(l0, 2); l1 += __shfl_xor(l1, 2); l2 += __shfl_xor(l2, 2); l3 += __shfl_xor(l3, 2);
        l0 += __shfl_xor(l0, 4); l1 += __shfl_xor(l1, 4); l2 += __shfl_xor(l2, 4); l3 += __shfl_xor(l3, 4);
        ax[0][p] = l0; ax[1][p] = l1; ax[2][p] = l2; ax[3][p] = l3;
      }
    }

    // ---- softmax per pixel (redundant across c-lanes, no sync) ----
#pragma unroll
    for (int i = 0; i < 4; ++i) {
      float mx = -1e30f;
#pragma unroll
      for (int p = 0; p < 9; ++p) mx = fmaxf(mx, ax[i][p]);
      float dx = 0.f;
#pragma unroll
      for (int p = 0; p < 9; ++p) { ax[i][p] = __expf(ax[i][p] - mx); dx += ax[i][p]; }
      float ix = 1.f / dx;
#pragma unroll
      for (int p = 0; p < 9; ++p) ax[i][p] *= ix;
    }

    // ---- V phase -> Ao ----
    {
      float t[16];
#pragma unroll
      for (int i = 0; i < 4; ++i)
#pragma unroll
        for (int j = 0; j < 4; ++j)
          t[i * 4 + j] = hal[tbase + 1440 + i * 18 + j];
      float o0 = 0.f, o1 = 0.f, o2 = 0.f, o3 = 0.f;
#pragma unroll
      for (int p = 0; p < 9; ++p) {
        float v0 = Vb[p], v1 = Vb[p], v2 = Vb[p], v3 = Vb[p];
#pragma unroll
        for (int ry = 0; ry < 3; ++ry)
#pragma unroll
          for (int rx = 0; rx < 3; ++rx) {
            float a = A[p * 9 + ry * 3 + rx];
            v0 = fmaf(a, t[ry * 4 + rx],           v0);
            v1 = fmaf(a, t[ry * 4 + rx + 1],       v1);
            v2 = fmaf(a, t[(ry + 1) * 4 + rx],     v2);
            v3 = fmaf(a, t[(ry + 1) * 4 + rx + 1], v3);
          }
        o0 = fmaf(ax[0][p], v0, o0);
        o1 = fmaf(ax[1][p], v1, o1);
        o2 = fmaf(ax[2][p], v2, o2);
        o3 = fmaf(ax[3][p], v3, o3);
      }
      int px0 = (2 * w) * 16 + 2 * qk;       // (dy,dx)=(0,0)
      int px1 = px0 + 1;
      int px2 = px0 + 16;
      int px3 = px0 + 17;
      Ao[px0][((n ^ (px0 & 7)) << 3) + c] = f2b(o0);
      Ao[px1][((n ^ (px1 & 7)) << 3) + c] = f2b(o1);
      Ao[px2][((n ^ (px2 & 7)) << 3) + c] = f2b(o2);
      Ao[px3][((n ^ (px3 & 7)) << 3) + c] = f2b(o3);
    }
  }
  __syncthreads();

  // ---- proj epilogue: out(256d x 128px) = pw(256x64) @ Ao^T, K=64 (4 waves x 4 bands) ----
  const int lane = tid & 63;
  f32x4 acc[4][8];
#pragma unroll
  for (int t = 0; t < 4; ++t)
#pragma unroll
    for (int st = 0; st < 8; ++st) acc[t][st] = (f32x4){0.f, 0.f, 0.f, 0.f};

  const int nn = lane & 15, g = lane >> 4;
#pragma unroll
  for (int c32 = 0; c32 < 2; ++c32) {
    bf16x8 af[4];
#pragma unroll
    for (int t = 0; t < 4; ++t) {
      int band = w * 4 + t;
      af[t] = *(const bf16x8*)(pwf + ((size_t)(band * 2 + c32) * 64 + lane) * 8);
    }
#pragma unroll
    for (int st = 0; st < 8; ++st) {
      int s_row = st * 16 + nn;
      int stc = (c32 * 4 + g) ^ (s_row & 7);
      bf16x8 bf = *(const bf16x8*)&Ao[s_row][stc * 8];
#pragma unroll
      for (int t = 0; t < 4; ++t)
        acc[t][st] = __builtin_amdgcn_mfma_f32_16x16x32_bf16(af[t], bf, acc[t][st], 0, 0, 0);
    }
  }

  float bias[4][4];
#pragma unroll
  for (int t = 0; t < 4; ++t)
#pragma unroll
    for (int r = 0; r < 4; ++r) bias[t][r] = pb[(w * 4 + t) * 16 + g * 4 + r];

  float* ob = out + ((size_t)b << 20);
#pragma unroll
  for (int t = 0; t < 4; ++t) {
    int d0 = (w * 4 + t) * 16 + g * 4;
#pragma unroll
    for (int st = 0; st < 8; ++st) {
      int sp = (h0 + st) * 64 + w0 + nn;
#pragma unroll
      for (int r = 0; r < 4; ++r)
        ob[(size_t)(d0 + r) * HW + sp] = acc[t][st][r] + bias[t][r];
    }
  }
}

extern "C" void kernel_launch(void* const* d_in, const int* in_sizes, int n_in,
                              void* d_out, int out_size, void* d_ws, size_t ws_size,
                              hipStream_t stream) {
  (void)in_sizes; (void)n_in; (void)out_size; (void)ws_size;
  const float* x    = (const float*)d_in[0];
  const float* qw   = (const float*)d_in[5];
  const float* qb   = (const float*)d_in[6];
  const float* dcb  = (const float*)d_in[7];
  const float* w1   = (const float*)d_in[8];
  const float* dc1b = (const float*)d_in[9];
  const float* rpb  = (const float*)d_in[10];
  const float* pw   = (const float*)d_in[11];
  const float* pb   = (const float*)d_in[12];

  // Workspace (64 MiB, proven-safe):
  // [0, 25165824)            qkvt bf16 (B,192,4096)
  // [25165824, 25264128)     qwf  (6144*16 B)
  // [29360128, 29364352)     prep (1056 floats)
  // [30408704, 30441472)     pwf  (2048*16 B)
  unsigned short* qkvt = (unsigned short*)d_ws;
  unsigned short* qwf  = (unsigned short*)((char*)d_ws + 25165824);
  float* prep          = (float*)((char*)d_ws + 29360128);
  unsigned short* pwf  = (unsigned short*)((char*)d_ws + 30408704);

  cast_all<<<33, 256, 0, stream>>>(qw, qwf, dcb, w1, dc1b, rpb, prep, pw, pwf);
  qkv_mfma<<<dim3(32, BB), 256, 0, stream>>>(x, qwf, qb, qkvt);
  attn_proj<<<dim3(BB, 32), 256, 0, stream>>>(qkvt, prep, pwf, pb, (float*)d_out);
}